// Round 4
// baseline (742.522 us; speedup 1.0000x reference)
//
#include <hip/hip_runtime.h>

// GsumLayer: out[b] = a[b] @ x[b], B=8, N=4096, D=32, fp32 in/out.
//
// v4: minimal pure-stream MFMA kernel (R2 structure, best measured, stripped).
//   - split-bf16 MFMA: a ~= ah+al, x ~= xh+xl; keep xh*ah + xl*ah + xh*al.
//   - a (537 MB): HBM -> VGPR direct, per-lane row reads, 4-step-deep pipeline
//     (8 KB/wave in flight; 64 KB/CU >> 12 KB BW*latency product).
//   - x: pre-split/transposed once to bf16 xT_hi/lo [B][32][4096] in d_ws
//     (4 MB, L2-resident); fragments are direct 16B L2 loads, 2 steps deep.
//   - ZERO LDS, ZERO barriers, no sched pinning (R3's pinning regressed).
//   - XCD-chunked block swizzle (512 % 8 == 0, bijective): each XCD's L2
//     caches only its own batch's 512 KB of xT.
//
// Input order per setup_inputs(): d_in[0] = x [B,N,D], d_in[1] = a [B,N,N].

#define GN 4096
#define GD 32
#define GB 8
#define NCH 16            // chunks of 8 k-steps (step = 32 k)
#define TILE_N 64         // 4 waves x 16 rows
#define NT 256

typedef float f32x4 __attribute__((ext_vector_type(4)));
typedef short s16x8 __attribute__((ext_vector_type(8)));

// ---------------- pre-kernel: x [B,N,D] fp32 -> xT_hi/xT_lo [B,D,N] bf16 ---
__global__ __launch_bounds__(256, 4) void xprep(
    const float* __restrict__ x,
    unsigned short* __restrict__ xth,
    unsigned short* __restrict__ xtl)
{
    const int t  = threadIdx.x;
    const int b  = blockIdx.x >> 5;   // 0..7
    const int kc = blockIdx.x & 31;   // 32 chunks of 128 k
    const int d  = t & 31;
    const int kb = t >> 5;            // 0..7
    const int k0 = kc * 128 + kb * 16;
    const float* xb = x + (long long)b * GN * GD;

    __attribute__((aligned(16))) unsigned short hi[16];
    __attribute__((aligned(16))) unsigned short lo[16];
    #pragma unroll
    for (int j = 0; j < 16; ++j) {
        float f = xb[(long long)(k0 + j) * GD + d];   // lanes d=0..31 coalesced
        unsigned u  = __float_as_uint(f);
        unsigned hb = (u + 0x8000u) >> 16;
        float hif   = __uint_as_float(hb << 16);
        hi[j] = (unsigned short)hb;
        lo[j] = (unsigned short)((__float_as_uint(f - hif) + 0x8000u) >> 16);
    }
    long long ob = ((long long)(b * GD + d)) * GN + k0;
    *(s16x8*)(xth + ob)     = *(const s16x8*)&hi[0];
    *(s16x8*)(xth + ob + 8) = *(const s16x8*)&hi[8];
    *(s16x8*)(xtl + ob)     = *(const s16x8*)&lo[0];
    *(s16x8*)(xtl + ob + 8) = *(const s16x8*)&lo[8];
}

// ---------------- main kernel ---------------------------------------------
__global__ __launch_bounds__(NT, 2) void gsum_stream(
    const float* __restrict__ a,
    const unsigned short* __restrict__ xth,  // [GB][GD][GN] bf16 hi
    const unsigned short* __restrict__ xtl,  // [GB][GD][GN] bf16 lo
    float* __restrict__ out)
{
    const int t  = threadIdx.x;
    const int w  = t >> 6;        // wave 0..3
    const int l  = t & 63;
    const int m  = l & 15;        // MFMA row/col index
    const int kg = l >> 4;        // MFMA k-group 0..3

    // XCD-chunked bijective swizzle: XCD r handles batch r's 64 tiles.
    const int bid  = blockIdx.x;
    const int swz  = (bid & 7) * 64 + (bid >> 3);
    const int b    = swz >> 6;
    const int tile = swz & 63;
    const int n0   = tile * TILE_N + w * 16;

    // per-lane stream bases
    const float* arow = a + ((long long)b * GN + n0 + m) * GN + kg * 8;
    const unsigned short* xh0p = xth + (long long)(b * GD + m) * GN + kg * 8;
    const unsigned short* xh1p = xh0p + 16 * GN;
    const unsigned short* xl0p = xtl + (long long)(b * GD + m) * GN + kg * 8;
    const unsigned short* xl1p = xl0p + 16 * GN;

    f32x4 acc0 = {0.f, 0.f, 0.f, 0.f};
    f32x4 acc1 = {0.f, 0.f, 0.f, 0.f};
    f32x4 pa[4][2];   // a pipeline: 4 steps deep
    s16x8 xf[2][4];   // x fragment pipeline: 2 steps deep

    // ---- prologue: fill pipelines ----
    #pragma unroll
    for (int g = 0; g < 4; ++g) {
        pa[g][0] = *(const f32x4*)(arow + g * 32);
        pa[g][1] = *(const f32x4*)(arow + g * 32 + 4);
    }
    #pragma unroll
    for (int g = 0; g < 2; ++g) {
        xf[g][0] = *(const s16x8*)(xh0p + g * 32);
        xf[g][1] = *(const s16x8*)(xh1p + g * 32);
        xf[g][2] = *(const s16x8*)(xl0p + g * 32);
        xf[g][3] = *(const s16x8*)(xl1p + g * 32);
    }

#define STEP_BODY(S, REFILL_A, REFILL_X)                                        \
    {                                                                           \
        f32x4 a0 = pa[(S) & 3][0], a1 = pa[(S) & 3][1];                         \
        s16x8 vh0 = xf[(S) & 1][0], vh1 = xf[(S) & 1][1];                       \
        s16x8 vl0 = xf[(S) & 1][2], vl1 = xf[(S) & 1][3];                       \
        if (REFILL_A) {                                                         \
            const int ga = c * 8 + (S) + 4;                                     \
            pa[(S) & 3][0] = *(const f32x4*)(arow + ga * 32);                   \
            pa[(S) & 3][1] = *(const f32x4*)(arow + ga * 32 + 4);               \
        }                                                                       \
        if (REFILL_X) {                                                         \
            const int gx = c * 8 + (S) + 2;                                     \
            xf[(S) & 1][0] = *(const s16x8*)(xh0p + gx * 32);                   \
            xf[(S) & 1][1] = *(const s16x8*)(xh1p + gx * 32);                   \
            xf[(S) & 1][2] = *(const s16x8*)(xl0p + gx * 32);                   \
            xf[(S) & 1][3] = *(const s16x8*)(xl1p + gx * 32);                   \
        }                                                                       \
        s16x8 ahi, alo;                                                         \
        _Pragma("unroll")                                                       \
        for (int e = 0; e < 4; ++e) {                                           \
            {                                                                   \
                unsigned u  = __float_as_uint(a0[e]);                           \
                unsigned hb = (u + 0x8000u) >> 16;                              \
                ahi[e] = (short)hb;                                             \
                float hif = __uint_as_float(hb << 16);                          \
                alo[e] = (short)((__float_as_uint(a0[e] - hif) + 0x8000u) >> 16); \
            }                                                                   \
            {                                                                   \
                unsigned u  = __float_as_uint(a1[e]);                           \
                unsigned hb = (u + 0x8000u) >> 16;                              \
                ahi[4 + e] = (short)hb;                                         \
                float hif = __uint_as_float(hb << 16);                          \
                alo[4 + e] = (short)((__float_as_uint(a1[e] - hif) + 0x8000u) >> 16); \
            }                                                                   \
        }                                                                       \
        acc0 = __builtin_amdgcn_mfma_f32_16x16x32_bf16(vh0, ahi, acc0, 0, 0, 0); \
        acc1 = __builtin_amdgcn_mfma_f32_16x16x32_bf16(vh1, ahi, acc1, 0, 0, 0); \
        acc0 = __builtin_amdgcn_mfma_f32_16x16x32_bf16(vl0, ahi, acc0, 0, 0, 0); \
        acc1 = __builtin_amdgcn_mfma_f32_16x16x32_bf16(vl1, ahi, acc1, 0, 0, 0); \
        acc0 = __builtin_amdgcn_mfma_f32_16x16x32_bf16(vh0, alo, acc0, 0, 0, 0); \
        acc1 = __builtin_amdgcn_mfma_f32_16x16x32_bf16(vh1, alo, acc1, 0, 0, 0); \
    }

    // ---- main loop: chunks 0..14, full refills (all in-bounds) ----
    for (int c = 0; c < NCH - 1; ++c) {
        #pragma unroll
        for (int s = 0; s < 8; ++s) {
            STEP_BODY(s, true, true)
        }
    }
    // ---- tail chunk 15: refill a only for s<4 (g<=127), x only for s<6 ----
    {
        const int c = NCH - 1;
        #pragma unroll
        for (int s = 0; s < 8; ++s) {
            STEP_BODY(s, (s < 4), (s < 6))
        }
    }
#undef STEP_BODY

    // ---- epilogue: D col = lane&15 (n), row = kg*4+j (d) ----
    float* Ob = out + ((long long)b * GN + n0 + m) * GD + kg * 4;
    #pragma unroll
    for (int j = 0; j < 4; ++j) {
        Ob[j]      = acc0[j];   // d = kg*4 + j
        Ob[16 + j] = acc1[j];   // d = 16 + kg*4 + j
    }
}

extern "C" void kernel_launch(void* const* d_in, const int* in_sizes, int n_in,
                              void* d_out, int out_size, void* d_ws, size_t ws_size,
                              hipStream_t stream) {
    const float* x = (const float*)d_in[0];  // [B, N, D]
    const float* a = (const float*)d_in[1];  // [B, N, N]
    float* out = (float*)d_out;              // [B, N, D]

    // workspace: xT_hi (2 MB) + xT_lo (2 MB), bf16 [B][32][4096]
    unsigned short* xth = (unsigned short*)d_ws;
    unsigned short* xtl = xth + (long long)GB * GD * GN;

    xprep<<<dim3(GB * 32), dim3(256), 0, stream>>>(x, xth, xtl);
    gsum_stream<<<dim3(GB * (GN / TILE_N)), dim3(NT), 0, stream>>>(a, xth, xtl, out);
}